// Round 6
// baseline (280.816 us; speedup 1.0000x reference)
//
#include <hip/hip_runtime.h>

using bf16   = __bf16;
using bf16x8 = __attribute__((ext_vector_type(8))) __bf16;
using f32x4  = __attribute__((ext_vector_type(4))) float;
using u32x4  = __attribute__((ext_vector_type(4))) unsigned;

// B=2 T=2048 D=2048 H=32 KVH=8 HD=64 GROUPS=4 ; M=B*T=4096 ; NQKV=3072
#define T_SEQ 2048
#define NQKV 3072

__device__ __forceinline__ void async_cp16(const bf16* g, bf16* l) {
  __builtin_amdgcn_global_load_lds((__attribute__((address_space(1))) void*)(void*)g,
                                   (__attribute__((address_space(3))) void*)l, 16, 0, 0);
}

// ---------------- fp32 -> bf16 elementwise convert (8 elems/thread) -------------
__global__ __launch_bounds__(256) void cvt_kernel(const float* __restrict__ in,
                                                  bf16* __restrict__ out) {
  long i = ((long)blockIdx.x * 256 + threadIdx.x) * 8;
  float4 a = *(const float4*)(in + i);
  float4 c = *(const float4*)(in + i + 4);
  bf16x8 v;
  v[0] = (bf16)a.x; v[1] = (bf16)a.y; v[2] = (bf16)a.z; v[3] = (bf16)a.w;
  v[4] = (bf16)c.x; v[5] = (bf16)c.y; v[6] = (bf16)c.z; v[7] = (bf16)c.w;
  *(bf16x8*)(out + i) = v;
}

// ------------- transpose + convert: out[n][k] = (bf16)in[k][n] ------------------
__global__ __launch_bounds__(256) void transpose_cvt(const float* __restrict__ in,
                                                     bf16* __restrict__ out,
                                                     int R, int C) {
  __shared__ float tile[32][33];
  const int tc = blockIdx.x * 32;  // col tile (n)
  const int tr = blockIdx.y * 32;  // row tile (k)
  const int t = threadIdx.x;
  const int lr = t >> 5;   // 0..7
  const int lc = t & 31;
#pragma unroll
  for (int i = 0; i < 4; ++i)
    tile[lr + i * 8][lc] = in[(size_t)(tr + lr + i * 8) * C + tc + lc];
  __syncthreads();
#pragma unroll
  for (int i = 0; i < 4; ++i)
    out[(size_t)(tc + lr + i * 8) * R + tr + lc] = (bf16)tile[lc][lr + i * 8];
}

// ------------- bf16 transpose of the V block of qkv -----------------------------
// in:  qkv[4096][3072], V at cols 2560..3071
// out: vT[b][512][2048] : vT[((r>>11)*512 + c)*2048 + (r&2047)] = qkv[r][2560+c]
__global__ __launch_bounds__(256) void transpose_v(const bf16* __restrict__ in,
                                                   bf16* __restrict__ out) {
  __shared__ bf16 tile[32][33];
  const int c0 = blockIdx.x * 32;   // 0..480
  const int r0 = blockIdx.y * 32;   // 0..4064
  const int t = threadIdx.x;
  const int lr = t >> 5;
  const int lc = t & 31;
#pragma unroll
  for (int i = 0; i < 4; ++i)
    tile[lr + i * 8][lc] = in[(size_t)(r0 + lr + i * 8) * NQKV + 2560 + c0 + lc];
  __syncthreads();
#pragma unroll
  for (int i = 0; i < 4; ++i) {
    int c = c0 + lr + i * 8;
    int r = r0 + lc;
    out[(size_t)((r >> 11) * 512 + c) * 2048 + (r & 2047)] = tile[lc][lr + i * 8];
  }
}

// ------------- 8-phase deep-pipelined GEMM: C = A[M][K] * Bt[N][K]^T -------------
// r13: faithful port of the 256^2 8-phase schedule (T3+T4+T5). r12's coarse
// 2-deep split regressed (MfmaUtil 33%) exactly as m196 predicts; the lever is
// the per-phase {ds_read subtile | 1 half-tile stage | barrier | lgkmcnt(0) |
// 16 MFMA | barrier} interleave with COUNTED vmcnt only at tile boundaries.
// Geometry: 512 thr = 8 waves (2M x 4N), BM=256, BK=64; per-wave 128 x BN/4;
// 4 phases/K-tile split by (ks, m-half); B-frags reused across m-halves.
// Staging ledger (stage = 2 gload_lds/thread, half-tile = 128 rows):
//   tile t: ph0 -> B-H1(t+1) into buf^1   (free: holds dead t-1 data)
//           ph1 -> A-H0(t+1) into buf^1
//           ph2 -> A-H1(t+1) into buf^1
//           ph3 -> B-H0(t+2) into buf     (B region freed by ph2 post-barrier:
//                                          all waves' B reads are ks0@ph0,ks1@ph2)
//   boundary: vmcnt(2) (newest stage floats) + s_barrier => all waves' staged
//   data landed (per-wave vmcnt + barrier covers cross-wave staging).
//   vmcnt(0) only at the last tile. Prologue: A0,A1,BH0,BH1 of tile0 + BH0(1);
//   first vmcnt(2) forces exactly tile 0.
// BN=128 (gemm2, full 256-block fill): B tile = 128 rows = one stage; ph0
// stages nothing, ph3 stages B(t+2). Ledger gives the same vmcnt(2).
// Spill tripwire: WRITE_SIZE inflation on gemm dispatches.
template <int KDIM, int BN, bool OUT_BF16>
__global__ __launch_bounds__(512, 2)
void gemm8p_kernel(const bf16* __restrict__ A, const bf16* __restrict__ Bt,
                   void* __restrict__ Cout, int Ndim) {
  constexpr int NT  = KDIM / 64;
  constexpr int NFR = BN / 64;            // N-frags per wave: 4 or 2
  __shared__ __attribute__((aligned(16))) bf16 As[2][256 * 64];
  __shared__ __attribute__((aligned(16))) bf16 Bs[2][BN * 64];

  const int tid  = threadIdx.x;
  const int lane = tid & 63;
  const int wave = tid >> 6;              // 0..7
  const int l16  = lane & 15;
  const int q4   = lane >> 4;
  const int wm   = (wave >> 2) * 128;     // wave M base in tile
  const int wn   = (wave & 3) * (BN / 4); // wave N base in tile

  const long m0 = (long)blockIdx.y * 256;
  const long n0 = (long)blockIdx.x * BN;
  const bf16* Ag = A + m0 * (long)KDIM;
  const bf16* Bg = Bt + n0 * (long)KDIM;

  f32x4 acc[8][NFR] = {};

  // stage one 128-row half-tile (2 x global_load_lds / thread), swizzled chunks
  auto stageA = [&](int buf, int kt, int h) {
    const long k0 = (long)kt * 64;
#pragma unroll
    for (int rr = 0; rr < 2; ++rr) {
      int ci  = rr * 512 + tid;           // 0..1023
      int row = h * 128 + (ci >> 3);
      int ch  = (ci & 7) ^ (row & 7);
      async_cp16(Ag + (long)row * KDIM + k0 + ch * 8,
                 &As[buf][(size_t)row * 64 + (ci & 7) * 8]);
    }
  };
  auto stageB = [&](int buf, int kt, int h) {
    const long k0 = (long)kt * 64;
#pragma unroll
    for (int rr = 0; rr < 2; ++rr) {
      int ci  = rr * 512 + tid;
      int row = h * 128 + (ci >> 3);
      int ch  = (ci & 7) ^ (row & 7);
      async_cp16(Bg + (long)row * KDIM + k0 + ch * 8,
                 &Bs[buf][(size_t)row * 64 + (ci & 7) * 8]);
    }
  };

  // prologue: all of tile 0, plus the B-H0(1) owed by "tile -1 ph3"
  stageA(0, 0, 0);
  stageA(0, 0, 1);
  stageB(0, 0, 0);
  if constexpr (BN == 256) stageB(0, 0, 1);
  stageB(1, 1, 0);

  bf16x8 aF[4], bF[NFR];

  for (int t = 0; t < NT; ++t) {
    const int cur = t & 1, nxt = cur ^ 1;
    if (t < NT - 1) asm volatile("s_waitcnt vmcnt(2)" ::: "memory");
    else            asm volatile("s_waitcnt vmcnt(0)" ::: "memory");
    __builtin_amdgcn_s_barrier();

    // ---- phase 0: ks=0, m-half 0 ----
#pragma unroll
    for (int mt = 0; mt < 4; ++mt) {
      int row = wm + mt * 16 + l16;
      aF[mt] = *(const bf16x8*)&As[cur][row * 64 + (q4 ^ (row & 7)) * 8];
    }
#pragma unroll
    for (int nt = 0; nt < NFR; ++nt) {
      int row = wn + nt * 16 + l16;
      bF[nt] = *(const bf16x8*)&Bs[cur][row * 64 + (q4 ^ (row & 7)) * 8];
    }
    if constexpr (BN == 256) { if (t + 1 < NT) stageB(nxt, t + 1, 1); }
    __builtin_amdgcn_s_barrier();
    asm volatile("s_waitcnt lgkmcnt(0)" ::: "memory");
    __builtin_amdgcn_sched_barrier(0);
    __builtin_amdgcn_s_setprio(1);
#pragma unroll
    for (int mt = 0; mt < 4; ++mt)
#pragma unroll
      for (int nt = 0; nt < NFR; ++nt)
        acc[mt][nt] = __builtin_amdgcn_mfma_f32_16x16x32_bf16(aF[mt], bF[nt],
                                                              acc[mt][nt], 0, 0, 0);
    __builtin_amdgcn_s_setprio(0);
    __builtin_amdgcn_s_barrier();

    // ---- phase 1: ks=0, m-half 1 (B-frags reused) ----
#pragma unroll
    for (int mt = 0; mt < 4; ++mt) {
      int row = wm + 64 + mt * 16 + l16;
      aF[mt] = *(const bf16x8*)&As[cur][row * 64 + (q4 ^ (row & 7)) * 8];
    }
    if (t + 1 < NT) stageA(nxt, t + 1, 0);
    __builtin_amdgcn_s_barrier();
    asm volatile("s_waitcnt lgkmcnt(0)" ::: "memory");
    __builtin_amdgcn_sched_barrier(0);
    __builtin_amdgcn_s_setprio(1);
#pragma unroll
    for (int mt = 0; mt < 4; ++mt)
#pragma unroll
      for (int nt = 0; nt < NFR; ++nt)
        acc[4 + mt][nt] = __builtin_amdgcn_mfma_f32_16x16x32_bf16(aF[mt], bF[nt],
                                                                  acc[4 + mt][nt], 0, 0, 0);
    __builtin_amdgcn_s_setprio(0);
    __builtin_amdgcn_s_barrier();

    // ---- phase 2: ks=1, m-half 0 ----
#pragma unroll
    for (int mt = 0; mt < 4; ++mt) {
      int row = wm + mt * 16 + l16;
      aF[mt] = *(const bf16x8*)&As[cur][row * 64 + ((4 + q4) ^ (row & 7)) * 8];
    }
#pragma unroll
    for (int nt = 0; nt < NFR; ++nt) {
      int row = wn + nt * 16 + l16;
      bF[nt] = *(const bf16x8*)&Bs[cur][row * 64 + ((4 + q4) ^ (row & 7)) * 8];
    }
    if (t + 1 < NT) stageA(nxt, t + 1, 1);
    __builtin_amdgcn_s_barrier();
    asm volatile("s_waitcnt lgkmcnt(0)" ::: "memory");
    __builtin_amdgcn_sched_barrier(0);
    __builtin_amdgcn_s_setprio(1);
#pragma unroll
    for (int mt = 0; mt < 4; ++mt)
#pragma unroll
      for (int nt = 0; nt < NFR; ++nt)
        acc[mt][nt] = __builtin_amdgcn_mfma_f32_16x16x32_bf16(aF[mt], bF[nt],
                                                              acc[mt][nt], 0, 0, 0);
    __builtin_amdgcn_s_setprio(0);
    __builtin_amdgcn_s_barrier();   // frees ALL B reads of buf[cur] -> ph3 stage ok

    // ---- phase 3: ks=1, m-half 1 ----
#pragma unroll
    for (int mt = 0; mt < 4; ++mt) {
      int row = wm + 64 + mt * 16 + l16;
      aF[mt] = *(const bf16x8*)&As[cur][row * 64 + ((4 + q4) ^ (row & 7)) * 8];
    }
    if (t + 2 < NT) stageB(cur, t + 2, 0);   // B-H0 of t+2 into just-freed region
    __builtin_amdgcn_s_barrier();
    asm volatile("s_waitcnt lgkmcnt(0)" ::: "memory");
    __builtin_amdgcn_sched_barrier(0);
    __builtin_amdgcn_s_setprio(1);
#pragma unroll
    for (int mt = 0; mt < 4; ++mt)
#pragma unroll
      for (int nt = 0; nt < NFR; ++nt)
        acc[4 + mt][nt] = __builtin_amdgcn_mfma_f32_16x16x32_bf16(aF[mt], bF[nt],
                                                                  acc[4 + mt][nt], 0, 0, 0);
    __builtin_amdgcn_s_setprio(0);
    // no post-barrier: merged with next iteration's boundary barrier
  }

  // epilogue
#pragma unroll
  for (int idx = 0; idx < 8; ++idx) {
    const int mh = idx >> 2, mt = idx & 3;
#pragma unroll
    for (int nt = 0; nt < NFR; ++nt)
#pragma unroll
      for (int r = 0; r < 4; ++r) {
        long row = m0 + wm + mh * 64 + mt * 16 + q4 * 4 + r;
        long col = n0 + wn + nt * 16 + l16;
        float v = acc[idx][nt][r];
        if constexpr (OUT_BF16)
          ((bf16*)Cout)[row * Ndim + col] = (bf16)v;
        else
          ((float*)Cout)[row * Ndim + col] = v;
      }
  }
}

// ------------- causal GQA flash attention ---------------------------------------
// (unchanged from r11: operand-swapped QK^T, in-register P transpose via
// v_cvt_pk_bf16_f32 + permlane32/16_swap, bare v_exp_f32, launch_bounds(256,3).)
__global__ __launch_bounds__(256, 3)
void attn_kernel(const bf16* __restrict__ qkv, const bf16* __restrict__ vT,
                 bf16* __restrict__ outb) {
  __shared__ __attribute__((aligned(16))) bf16 Ks[64 * 64];   // swizzled chunks
  __shared__ __attribute__((aligned(16))) bf16 Vs[64 * 64];   // V^T tile, swizzled

  const int tid  = threadIdx.x;
  const int lane = tid & 63;
  const int wave = tid >> 6;
  const int l16  = lane & 15;
  const int q4   = lane >> 4;

  const int bid = blockIdx.x;
  const int qt  = 15 - (bid >> 6);   // heavy q-tiles dispatched first
  const int bh  = bid & 63;
  const int b   = bh >> 5;
  const int h   = bh & 31;
  const int kvh = h >> 2;
  const long rowbase = (long)b * T_SEQ;

  const int qrow0 = qt * 128;
  const int wq0   = qrow0 + wave * 32;
  const float cexp = 0.125f * 1.4426950408889634f;  // scale * log2(e), folded into Q

  // Q fragments in registers, pre-scaled by cexp (so P = exp2(S) directly)
  bf16x8 aq[2][2];
#pragma unroll
  for (int mt = 0; mt < 2; ++mt)
#pragma unroll
    for (int ks = 0; ks < 2; ++ks) {
      bf16x8 v = *(const bf16x8*)(qkv +
          (rowbase + wq0 + mt * 16 + l16) * (long)NQKV + h * 64 + ks * 32 + q4 * 8);
#pragma unroll
      for (int i = 0; i < 8; ++i) v[i] = (bf16)((float)v[i] * cexp);
      aq[mt][ks] = v;
    }

  // ones B-fragment: B[k][n=0]=1 -> accumulates row-sums of P into col 0
  bf16x8 ones_f;
#pragma unroll
  for (int i = 0; i < 8; ++i) ones_f[i] = (l16 == 0) ? (bf16)1.0f : (bf16)0.0f;

  f32x4 o[2][4] = {};
  f32x4 o_l[2] = {};

  const bf16* kbase = qkv + rowbase * (long)NQKV + 2048 + kvh * 64;
  const bf16* vbase = vT + ((long)b * 512 + kvh * 64) * 2048;

  for (int j0 = 0; j0 < qrow0 + 128; j0 += 64) {
    __syncthreads();
    {   // stage K and V^T: linear LDS chunk dest (conflict-free banks),
        // swizzled global chunk source (within the row's 128B window)
#pragma unroll
      for (int h2 = 0; h2 < 2; ++h2) {
        int ci  = h2 * 256 + tid;      // 0..511
        int row = ci >> 3;
        int ch  = (ci & 7) ^ (row & 7);
        *(bf16x8*)&Ks[ci * 8] =
            *(const bf16x8*)(kbase + (long)(j0 + row) * NQKV + ch * 8);
        *(bf16x8*)&Vs[ci * 8] =
            *(const bf16x8*)(vbase + (long)row * 2048 + j0 + ch * 8);
      }
    }
    __syncthreads();
    if (j0 > wq0 + 31) continue;   // tile entirely above diagonal for this wave

    // S^T = K Q^T  (operand-swapped: tiles [kv = nt][q = mt])
    f32x4 s[2][4] = {};
#pragma unroll
    for (int ks = 0; ks < 2; ++ks) {
      bf16x8 bk[4];
#pragma unroll
      for (int nt = 0; nt < 4; ++nt) {
        int row  = nt * 16 + l16;
        int slot = (ks * 4 + q4) ^ (row & 7);
        bk[nt] = *(const bf16x8*)&Ks[row * 64 + slot * 8];
      }
#pragma unroll
      for (int mt = 0; mt < 2; ++mt)
#pragma unroll
        for (int nt = 0; nt < 4; ++nt)
          s[mt][nt] = __builtin_amdgcn_mfma_f32_16x16x32_bf16(bk[nt], aq[mt][ks],
                                                              s[mt][nt], 0, 0, 0);
    }

    if (j0 + 63 > wq0) {   // diagonal tile: causal mask (S^T: row=kv, col=q)
#pragma unroll
      for (int mt = 0; mt < 2; ++mt)
#pragma unroll
        for (int nt = 0; nt < 4; ++nt)
#pragma unroll
          for (int r = 0; r < 4; ++r) {
            int rg = wq0 + mt * 16 + l16;          // q row
            int cg = j0 + nt * 16 + q4 * 4 + r;    // kv col
            if (cg > rg) s[mt][nt][r] = -__builtin_inff();
          }
    }

    // P = exp2(S^T) via bare v_exp_f32; pack pairs with v_cvt_pk_bf16_f32;
    // route packed words into PV A-fragments with permlane32/16_swap.
    bf16x8 ap[2][2];
#pragma unroll
    for (int mt = 0; mt < 2; ++mt) {
      unsigned pk0, pk1, pk2, pk3, pk4, pk5, pk6, pk7;  // pk[nt][j], named scalars
      {
        float p0 = __builtin_amdgcn_exp2f(s[mt][0][0]);
        float p1 = __builtin_amdgcn_exp2f(s[mt][0][1]);
        float p2 = __builtin_amdgcn_exp2f(s[mt][0][2]);
        float p3 = __builtin_amdgcn_exp2f(s[mt][0][3]);
        asm("v_cvt_pk_bf16_f32 %0, %1, %2" : "=v"(pk0) : "v"(p0), "v"(p1));
        asm("v_cvt_pk_bf16_f32 %0, %1, %2" : "=v"(pk1) : "v"(p2), "v"(p3));
      }
      {
        float p0 = __builtin_amdgcn_exp2f(s[mt][1][0]);
        float p1 = __builtin_amdgcn_exp2f(s[mt][1][1]);
        float p2 = __builtin_amdgcn_exp2f(s[mt][1][2]);
        float p3 = __builtin_amdgcn_exp2f(s[mt][1][3]);
        asm("v_cvt_pk_bf16_f32 %0, %1, %2" : "=v"(pk2) : "v"(p0), "v"(p1));
        asm("v_cvt_pk_bf16_f32 %0, %1, %2" : "=v"(pk3) : "v"(p2), "v"(p3));
      }
      {
        float p0 = __builtin_amdgcn_exp2f(s[mt][2][0]);
        float p1 = __builtin_amdgcn_exp2f(s[mt][2][1]);
        float p2 = __builtin_amdgcn_exp2f(s[mt][2][2]);
        float p3 = __builtin_amdgcn_exp2f(s[mt][2][3]);
        asm("v_cvt_pk_bf16_f32 %0, %1, %2" : "=v"(pk4) : "v"(p0), "v"(p1));
        asm("v_cvt_pk_bf16_f32 %0, %1, %2" : "=v"(pk5) : "v"(p2), "v"(p3));
      }
      {
        float p0 = __builtin_amdgcn_exp2f(s[mt][3][0]);
        float p1 = __builtin_amdgcn_exp2f(s[mt][3][1]);
        float p2 = __builtin_amdgcn_exp2f(s[mt][3][2]);
        float p3 = __builtin_amdgcn_exp2f(s[mt][3][3]);
        asm("v_cvt_pk_bf16_f32 %0, %1, %2" : "=v"(pk6) : "v"(p0), "v"(p1));
        asm("v_cvt_pk_bf16_f32 %0, %1, %2" : "=v"(pk7) : "v"(p2), "v"(p3));
      }
      // ks = 0: sources pk[0][*], pk[1][*]
      {
        unsigned a0 = pk0, b0 = pk2;
        asm("v_permlane32_swap_b32 %0, %1" : "+v"(a0), "+v"(b0));
        asm("v_permlane16_swap_b32 %0, %1" : "+v"(a0), "+v"(b0));
        unsigned a1 = pk1, b1 = pk3;
        asm("v_permlane32_swap_b32 %0, %1" : "+v"(a1), "+v"(b1));
        asm("v_permlane16_swap_b32 %0, %1" : "+v"(a1), "+v"(b1));
        u32x4 w; w.x = a0; w.y = a1; w.z = b0; w.w = b1;
        ap[mt][0] = __builtin_bit_cast(bf16x8, w);
      }
      // ks = 1: sources pk[2][*], pk[3][*]
      {
        unsigned a0 = pk4, b0 = pk6;
        asm("v_permlane32_swap_b32 %0, %1" : "+v"(a0), "+v"(b0));
        asm("v_permlane16_swap_b32 %0, %1" : "+v"(a0), "+v"(b0));
        unsigned a1 = pk5, b1 = pk7;
        asm("v_permlane32_swap_b32 %0, %1" : "+v"(a1), "+v"(b1));
        asm("v_permlane16_swap_b32 %0, %1" : "+v"(a1), "+v"(b1));
        u32x4 w; w.x = a0; w.y = a1; w.z = b0; w.w = b1;
        ap[mt][1] = __builtin_bit_cast(bf16x8, w);
      }
    }

    // O += P V ; ell += P 1
#pragma unroll
    for (int ks = 0; ks < 2; ++ks) {
      bf16x8 bv[4];
#pragma unroll
      for (int dt = 0; dt < 4; ++dt) {
        int row  = dt * 16 + l16;
        int slot = (ks * 4 + q4) ^ (row & 7);
        bv[dt] = *(const bf16x8*)&Vs[row * 64 + slot * 8];
      }
#pragma unroll
      for (int mt = 0; mt < 2; ++mt) {
#pragma unroll
        for (int dt = 0; dt < 4; ++dt)
          o[mt][dt] = __builtin_amdgcn_mfma_f32_16x16x32_bf16(ap[mt][ks], bv[dt],
                                                              o[mt][dt], 0, 0, 0);
        o_l[mt] = __builtin_amdgcn_mfma_f32_16x16x32_bf16(ap[mt][ks], ones_f,
                                                          o_l[mt], 0, 0, 0);
      }
    }
  }

  // epilogue: normalize (row-sum broadcast from col-0 lane) and store bf16
#pragma unroll
  for (int mt = 0; mt < 2; ++mt) {
    float inv[4];
#pragma unroll
    for (int r = 0; r < 4; ++r) {
      float lsum = __shfl(o_l[mt][r], lane & 48);   // lane q4*16 holds col 0
      inv[r] = 1.0f / lsum;
    }
#pragma unroll
    for (int dt = 0; dt < 4; ++dt)
#pragma unroll
      for (int r = 0; r < 4; ++r) {
        long row = rowbase + wq0 + mt * 16 + q4 * 4 + r;
        int col = h * 64 + dt * 16 + l16;
        outb[row * 2048 + col] = (bf16)(o[mt][dt][r] * inv[r]);
      }
  }
}

// --------------------------------------------------------------------------------
extern "C" void kernel_launch(void* const* d_in, const int* in_sizes, int n_in,
                              void* d_out, int out_size, void* d_ws, size_t ws_size,
                              hipStream_t stream) {
  const float* x   = (const float*)d_in[0];
  const float* wq  = (const float*)d_in[1];
  const float* wkv = (const float*)d_in[2];
  const float* wo  = (const float*)d_in[3];
  float* out = (float*)d_out;
  char* ws = (char*)d_ws;

  // ws layout (bytes):
  //   xbf  [4096*2048] bf16 @ 0          (16,777,216)  -- reused as attn output
  //   w1   [3072*2048] bf16 @ 16777216   (12,582,912)  -- wq^T | wkv^T ; reused as vT
  //   qkv  [4096*3072] bf16 @ 29360128   (25,165,824)
  //   woT  [2048*2048] bf16 @ 54525952 if ws allows, else aliases qkv after attn
  bf16* xbf  = (bf16*)(ws + 0);
  bf16* w1   = (bf16*)(ws + 16777216);
  bf16* qkv  = (bf16*)(ws + 29360128);
  bf16* attn = xbf;              // xbf dead after gemm1
  bf16* vT   = w1;               // w1 dead after gemm1

  const size_t need_parallel = 54525952u + 8388608u;
  bf16* woT;
  bool woT_early;
  if (ws_size >= need_parallel) {
    woT = (bf16*)(ws + 54525952);
    woT_early = true;
  } else {
    woT = qkv;                   // qkv dead after attention
    woT_early = false;
  }

  cvt_kernel<<<4096, 256, 0, stream>>>(x, xbf);
  transpose_cvt<<<dim3(64, 64), 256, 0, stream>>>(wq, w1, 2048, 2048);
  transpose_cvt<<<dim3(32, 64), 256, 0, stream>>>(wkv, w1 + 2048L * 2048, 2048, 1024);
  if (woT_early)
    transpose_cvt<<<dim3(64, 64), 256, 0, stream>>>(wo, woT, 2048, 2048);

  // qkv = [x@wq | x@wkv]  (BM=256, BN=256 -> 12x16 = 192 blocks)
  gemm8p_kernel<2048, 256, true><<<dim3(12, 16), 512, 0, stream>>>(xbf, w1, (void*)qkv, 3072);

  // vT overwrites w1 region (w1 no longer needed)
  transpose_v<<<dim3(16, 128), 256, 0, stream>>>(qkv, vT);

  attn_kernel<<<1024, 256, 0, stream>>>(qkv, vT, attn);

  if (!woT_early)
    transpose_cvt<<<dim3(64, 64), 256, 0, stream>>>(wo, woT, 2048, 2048);

  // out = attn @ wo  (BM=256, BN=128 -> 16x16 = 256 blocks, full CU fill)
  gemm8p_kernel<2048, 128, false><<<dim3(16, 16), 512, 0, stream>>>(attn, woT, (void*)out, 2048);
}

// Round 7
// 258.746 us; speedup vs baseline: 1.0853x; 1.0853x over previous
//
#include <hip/hip_runtime.h>

using bf16   = __bf16;
using bf16x8 = __attribute__((ext_vector_type(8))) __bf16;
using f32x4  = __attribute__((ext_vector_type(4))) float;
using u32x4  = __attribute__((ext_vector_type(4))) unsigned;

// B=2 T=2048 D=2048 H=32 KVH=8 HD=64 GROUPS=4 ; M=B*T=4096 ; NQKV=3072
#define T_SEQ 2048
#define NQKV 3072

__device__ __forceinline__ void async_cp16(const bf16* g, bf16* l) {
  __builtin_amdgcn_global_load_lds((__attribute__((address_space(1))) void*)(void*)g,
                                   (__attribute__((address_space(3))) void*)l, 16, 0, 0);
}

// ------------- fused prep: cvt(x) | wq^T | wkv^T | wo^T as z-slices -------------
// r14: one launch replaces 4 (cvt_kernel + 3 transpose_cvt) - removes 3 launch
// gaps; bodies identical to the proven standalone kernels.
__global__ __launch_bounds__(256) void prep_kernel(
    const float* __restrict__ x, bf16* __restrict__ xbf,
    const float* __restrict__ wq, const float* __restrict__ wkv,
    const float* __restrict__ wo, bf16* __restrict__ w1,
    bf16* __restrict__ woT) {
  const int z = blockIdx.z;
  if (z == 0) {                 // fp32 -> bf16 convert of x (64x64 blocks = 4096)
    long i = (((long)blockIdx.y * 64 + blockIdx.x) * 256 + threadIdx.x) * 8;
    float4 a = *(const float4*)(x + i);
    float4 c = *(const float4*)(x + i + 4);
    bf16x8 v;
    v[0] = (bf16)a.x; v[1] = (bf16)a.y; v[2] = (bf16)a.z; v[3] = (bf16)a.w;
    v[4] = (bf16)c.x; v[5] = (bf16)c.y; v[6] = (bf16)c.z; v[7] = (bf16)c.w;
    *(bf16x8*)(xbf + i) = v;
    return;
  }
  const float* in; bf16* out; int R, C;
  if (z == 1)      { in = wq;  out = w1;                R = 2048; C = 2048; }
  else if (z == 2) { if (blockIdx.x >= 32) return;
                     in = wkv; out = w1 + 2048L * 2048; R = 2048; C = 1024; }
  else             { in = wo;  out = woT;               R = 2048; C = 2048; }
  __shared__ float tile[32][33];
  const int tc = blockIdx.x * 32;
  const int tr = blockIdx.y * 32;
  const int t = threadIdx.x;
  const int lr = t >> 5;
  const int lc = t & 31;
#pragma unroll
  for (int i = 0; i < 4; ++i)
    tile[lr + i * 8][lc] = in[(size_t)(tr + lr + i * 8) * C + tc + lc];
  __syncthreads();
#pragma unroll
  for (int i = 0; i < 4; ++i)
    out[(size_t)(tc + lr + i * 8) * R + tr + lc] = (bf16)tile[lc][lr + i * 8];
}

// ------------- transpose + convert (standalone, for the late-wo path) ----------
__global__ __launch_bounds__(256) void transpose_cvt(const float* __restrict__ in,
                                                     bf16* __restrict__ out,
                                                     int R, int C) {
  __shared__ float tile[32][33];
  const int tc = blockIdx.x * 32;
  const int tr = blockIdx.y * 32;
  const int t = threadIdx.x;
  const int lr = t >> 5;
  const int lc = t & 31;
#pragma unroll
  for (int i = 0; i < 4; ++i)
    tile[lr + i * 8][lc] = in[(size_t)(tr + lr + i * 8) * C + tc + lc];
  __syncthreads();
#pragma unroll
  for (int i = 0; i < 4; ++i)
    out[(size_t)(tc + lr + i * 8) * R + tr + lc] = (bf16)tile[lc][lr + i * 8];
}

// ------------- bf16 transpose of the V block of qkv -----------------------------
// in:  qkv[4096][3072], V at cols 2560..3071
// out: vT[b][512][2048] : vT[((r>>11)*512 + c)*2048 + (r&2047)] = qkv[r][2560+c]
__global__ __launch_bounds__(256) void transpose_v(const bf16* __restrict__ in,
                                                   bf16* __restrict__ out) {
  __shared__ bf16 tile[32][33];
  const int c0 = blockIdx.x * 32;   // 0..480
  const int r0 = blockIdx.y * 32;   // 0..4064
  const int t = threadIdx.x;
  const int lr = t >> 5;
  const int lc = t & 31;
#pragma unroll
  for (int i = 0; i < 4; ++i)
    tile[lr + i * 8][lc] = in[(size_t)(r0 + lr + i * 8) * NQKV + 2560 + c0 + lc];
  __syncthreads();
#pragma unroll
  for (int i = 0; i < 4; ++i) {
    int c = c0 + lr + i * 8;
    int r = r0 + lc;
    out[(size_t)((r >> 11) * 512 + c) * 2048 + (r & 2047)] = tile[lc][lr + i * 8];
  }
}

// ------------- GEMM: C[M][N] = A[M][K] * Bt[N][K]^T  (bf16 in, fp32 acc) --------
// r14: reverted to the r4/m97-structure kernel (measured 55.2us/937TF gemm1).
// Both deep-pipeline rewrites (r12 coarse 2-deep, r13 8-phase port) REGRESSED
// (60.5us/33% and 70.1us/28% MfmaUtil): per-phase lgkmcnt(0)+sched_barrier(0)
// pins are the m141 failure mode, and at 1 block/CU there is no wave diversity
// across barriers. Do not re-attempt without the verbatim m201 template.
template <bool OUT_BF16>
__global__ __launch_bounds__(256, 3)
void gemm_kernel(const bf16* __restrict__ A, const bf16* __restrict__ Bt,
                 void* __restrict__ Cout, int Kdim, int Ndim) {
  __shared__ __attribute__((aligned(16))) bf16 As[128 * 64];
  __shared__ __attribute__((aligned(16))) bf16 Bs[128 * 64];
  const int tid  = threadIdx.x;
  const int lane = tid & 63;
  const int wave = tid >> 6;
  const int l16  = lane & 15;
  const int q4   = lane >> 4;
  const long m0 = (long)blockIdx.y * 128;
  const long n0 = (long)blockIdx.x * 128;
  const int wm = (wave >> 1) * 64;
  const int wn = (wave & 1) * 64;

  f32x4 acc[4][4] = {};

  for (int k0 = 0; k0 < Kdim; k0 += 64) {
    __syncthreads();
#pragma unroll
    for (int rr = 0; rr < 4; ++rr) {
      int ci  = rr * 256 + tid;     // 16B chunk index 0..1023
      int row = ci >> 3;
      int chp = ci & 7;             // swizzled LDS chunk slot
      int ch  = chp ^ (row & 7);    // global chunk
      async_cp16(A + (m0 + row) * (long)Kdim + k0 + ch * 8, &As[ci * 8]);
      async_cp16(Bt + (n0 + row) * (long)Kdim + k0 + ch * 8, &Bs[ci * 8]);
    }
    __syncthreads();
#pragma unroll
    for (int ks = 0; ks < 2; ++ks) {
      bf16x8 af[4], bfr[4];
#pragma unroll
      for (int mt = 0; mt < 4; ++mt) {
        int row = wm + mt * 16 + l16;
        int chp = (ks * 4 + q4) ^ (row & 7);
        af[mt] = *(const bf16x8*)&As[row * 64 + chp * 8];
      }
#pragma unroll
      for (int nt = 0; nt < 4; ++nt) {
        int row = wn + nt * 16 + l16;
        int chp = (ks * 4 + q4) ^ (row & 7);
        bfr[nt] = *(const bf16x8*)&Bs[row * 64 + chp * 8];
      }
#pragma unroll
      for (int mt = 0; mt < 4; ++mt)
#pragma unroll
        for (int nt = 0; nt < 4; ++nt)
          acc[mt][nt] = __builtin_amdgcn_mfma_f32_16x16x32_bf16(af[mt], bfr[nt],
                                                                acc[mt][nt], 0, 0, 0);
    }
  }
#pragma unroll
  for (int mt = 0; mt < 4; ++mt)
#pragma unroll
    for (int nt = 0; nt < 4; ++nt)
#pragma unroll
      for (int r = 0; r < 4; ++r) {
        long row = m0 + wm + mt * 16 + q4 * 4 + r;
        long col = n0 + wn + nt * 16 + l16;
        float v = acc[mt][nt][r];
        if constexpr (OUT_BF16)
          ((bf16*)Cout)[row * Ndim + col] = (bf16)v;
        else
          ((float*)Cout)[row * Ndim + col] = v;
      }
}

// ------------- causal GQA flash attention ---------------------------------------
// r14 on top of r11: T14 async-STAGE split. Previously the 4 global loads/tile
// sat fully exposed between the two barriers (every wave stalled each tile).
// Now: prologue loads tile 0 into regs; per tile {barrier; ds_write regs;
// barrier; ISSUE next tile's loads; compute} - HBM/L2 latency hides under
// QK^T+softmax+PV. +16 VGPR (fits the (256,3) cap; WRITE_SIZE = spill tripwire).
// Keeps: operand-swapped QK^T, in-register P transpose (cvt_pk + permlane
// 32/16 swaps), bare v_exp_f32, no Ps buffer.
__global__ __launch_bounds__(256, 3)
void attn_kernel(const bf16* __restrict__ qkv, const bf16* __restrict__ vT,
                 bf16* __restrict__ outb) {
  __shared__ __attribute__((aligned(16))) bf16 Ks[64 * 64];   // swizzled chunks
  __shared__ __attribute__((aligned(16))) bf16 Vs[64 * 64];   // V^T tile, swizzled

  const int tid  = threadIdx.x;
  const int lane = tid & 63;
  const int wave = tid >> 6;
  const int l16  = lane & 15;
  const int q4   = lane >> 4;

  const int bid = blockIdx.x;
  const int qt  = 15 - (bid >> 6);   // heavy q-tiles dispatched first
  const int bh  = bid & 63;
  const int b   = bh >> 5;
  const int h   = bh & 31;
  const int kvh = h >> 2;
  const long rowbase = (long)b * T_SEQ;

  const int qrow0 = qt * 128;
  const int wq0   = qrow0 + wave * 32;
  const float cexp = 0.125f * 1.4426950408889634f;  // scale * log2(e), folded into Q

  // Q fragments in registers, pre-scaled by cexp (so P = exp2(S) directly)
  bf16x8 aq[2][2];
#pragma unroll
  for (int mt = 0; mt < 2; ++mt)
#pragma unroll
    for (int ks = 0; ks < 2; ++ks) {
      bf16x8 v = *(const bf16x8*)(qkv +
          (rowbase + wq0 + mt * 16 + l16) * (long)NQKV + h * 64 + ks * 32 + q4 * 8);
#pragma unroll
      for (int i = 0; i < 8; ++i) v[i] = (bf16)((float)v[i] * cexp);
      aq[mt][ks] = v;
    }

  // ones B-fragment: B[k][n=0]=1 -> accumulates row-sums of P into col 0
  bf16x8 ones_f;
#pragma unroll
  for (int i = 0; i < 8; ++i) ones_f[i] = (l16 == 0) ? (bf16)1.0f : (bf16)0.0f;

  f32x4 o[2][4] = {};
  f32x4 o_l[2] = {};

  const bf16* kbase = qkv + rowbase * (long)NQKV + 2048 + kvh * 64;
  const bf16* vbase = vT + ((long)b * 512 + kvh * 64) * 2048;

  const int ntiles = (qrow0 + 128) >> 6;

  // T14 prologue: tile 0 -> regs
  bf16x8 kr[2], vr[2];
#pragma unroll
  for (int h2 = 0; h2 < 2; ++h2) {
    int ci = h2 * 256 + tid, row = ci >> 3, ch = (ci & 7) ^ (row & 7);
    kr[h2] = *(const bf16x8*)(kbase + (long)row * NQKV + ch * 8);
    vr[h2] = *(const bf16x8*)(vbase + (long)row * 2048 + ch * 8);
  }

  for (int t = 0; t < ntiles; ++t) {
    const int j0 = t * 64;
    __syncthreads();                     // all waves done reading prev tile's LDS
#pragma unroll
    for (int h2 = 0; h2 < 2; ++h2) {     // regs -> LDS (vmcnt wait is implicit)
      int ci = h2 * 256 + tid;
      *(bf16x8*)&Ks[ci * 8] = kr[h2];
      *(bf16x8*)&Vs[ci * 8] = vr[h2];
    }
    __syncthreads();                     // LDS ready
    if (t + 1 < ntiles) {                // issue next tile's loads; land during compute
      const int jn = j0 + 64;
#pragma unroll
      for (int h2 = 0; h2 < 2; ++h2) {
        int ci = h2 * 256 + tid, row = ci >> 3, ch = (ci & 7) ^ (row & 7);
        kr[h2] = *(const bf16x8*)(kbase + (long)(jn + row) * NQKV + ch * 8);
        vr[h2] = *(const bf16x8*)(vbase + (long)row * 2048 + jn + ch * 8);
      }
    }
    if (j0 > wq0 + 31) continue;   // tile entirely above diagonal for this wave

    // S^T = K Q^T  (operand-swapped: tiles [kv = nt][q = mt])
    f32x4 s[2][4] = {};
#pragma unroll
    for (int ks = 0; ks < 2; ++ks) {
      bf16x8 bk[4];
#pragma unroll
      for (int nt = 0; nt < 4; ++nt) {
        int row  = nt * 16 + l16;
        int slot = (ks * 4 + q4) ^ (row & 7);
        bk[nt] = *(const bf16x8*)&Ks[row * 64 + slot * 8];
      }
#pragma unroll
      for (int mt = 0; mt < 2; ++mt)
#pragma unroll
        for (int nt = 0; nt < 4; ++nt)
          s[mt][nt] = __builtin_amdgcn_mfma_f32_16x16x32_bf16(bk[nt], aq[mt][ks],
                                                              s[mt][nt], 0, 0, 0);
    }

    if (j0 + 63 > wq0) {   // diagonal tile: causal mask (S^T: row=kv, col=q)
#pragma unroll
      for (int mt = 0; mt < 2; ++mt)
#pragma unroll
        for (int nt = 0; nt < 4; ++nt)
#pragma unroll
          for (int r = 0; r < 4; ++r) {
            int rg = wq0 + mt * 16 + l16;          // q row
            int cg = j0 + nt * 16 + q4 * 4 + r;    // kv col
            if (cg > rg) s[mt][nt][r] = -__builtin_inff();
          }
    }

    // P = exp2(S^T) via bare v_exp_f32; pack pairs with v_cvt_pk_bf16_f32;
    // route packed words into PV A-fragments with permlane32/16_swap.
    bf16x8 ap[2][2];
#pragma unroll
    for (int mt = 0; mt < 2; ++mt) {
      unsigned pk0, pk1, pk2, pk3, pk4, pk5, pk6, pk7;  // pk[nt][j], named scalars
      {
        float p0 = __builtin_amdgcn_exp2f(s[mt][0][0]);
        float p1 = __builtin_amdgcn_exp2f(s[mt][0][1]);
        float p2 = __builtin_amdgcn_exp2f(s[mt][0][2]);
        float p3 = __builtin_amdgcn_exp2f(s[mt][0][3]);
        asm("v_cvt_pk_bf16_f32 %0, %1, %2" : "=v"(pk0) : "v"(p0), "v"(p1));
        asm("v_cvt_pk_bf16_f32 %0, %1, %2" : "=v"(pk1) : "v"(p2), "v"(p3));
      }
      {
        float p0 = __builtin_amdgcn_exp2f(s[mt][1][0]);
        float p1 = __builtin_amdgcn_exp2f(s[mt][1][1]);
        float p2 = __builtin_amdgcn_exp2f(s[mt][1][2]);
        float p3 = __builtin_amdgcn_exp2f(s[mt][1][3]);
        asm("v_cvt_pk_bf16_f32 %0, %1, %2" : "=v"(pk2) : "v"(p0), "v"(p1));
        asm("v_cvt_pk_bf16_f32 %0, %1, %2" : "=v"(pk3) : "v"(p2), "v"(p3));
      }
      {
        float p0 = __builtin_amdgcn_exp2f(s[mt][2][0]);
        float p1 = __builtin_amdgcn_exp2f(s[mt][2][1]);
        float p2 = __builtin_amdgcn_exp2f(s[mt][2][2]);
        float p3 = __builtin_amdgcn_exp2f(s[mt][2][3]);
        asm("v_cvt_pk_bf16_f32 %0, %1, %2" : "=v"(pk4) : "v"(p0), "v"(p1));
        asm("v_cvt_pk_bf16_f32 %0, %1, %2" : "=v"(pk5) : "v"(p2), "v"(p3));
      }
      {
        float p0 = __builtin_amdgcn_exp2f(s[mt][3][0]);
        float p1 = __builtin_amdgcn_exp2f(s[mt][3][1]);
        float p2 = __builtin_amdgcn_exp2f(s[mt][3][2]);
        float p3 = __builtin_amdgcn_exp2f(s[mt][3][3]);
        asm("v_cvt_pk_bf16_f32 %0, %1, %2" : "=v"(pk6) : "v"(p0), "v"(p1));
        asm("v_cvt_pk_bf16_f32 %0, %1, %2" : "=v"(pk7) : "v"(p2), "v"(p3));
      }
      // ks = 0: sources pk[0][*], pk[1][*]
      {
        unsigned a0 = pk0, b0 = pk2;
        asm("v_permlane32_swap_b32 %0, %1" : "+v"(a0), "+v"(b0));
        asm("v_permlane16_swap_b32 %0, %1" : "+v"(a0), "+v"(b0));
        unsigned a1 = pk1, b1 = pk3;
        asm("v_permlane32_swap_b32 %0, %1" : "+v"(a1), "+v"(b1));
        asm("v_permlane16_swap_b32 %0, %1" : "+v"(a1), "+v"(b1));
        u32x4 w; w.x = a0; w.y = a1; w.z = b0; w.w = b1;
        ap[mt][0] = __builtin_bit_cast(bf16x8, w);
      }
      // ks = 1: sources pk[2][*], pk[3][*]
      {
        unsigned a0 = pk4, b0 = pk6;
        asm("v_permlane32_swap_b32 %0, %1" : "+v"(a0), "+v"(b0));
        asm("v_permlane16_swap_b32 %0, %1" : "+v"(a0), "+v"(b0));
        unsigned a1 = pk5, b1 = pk7;
        asm("v_permlane32_swap_b32 %0, %1" : "+v"(a1), "+v"(b1));
        asm("v_permlane16_swap_b32 %0, %1" : "+v"(a1), "+v"(b1));
        u32x4 w; w.x = a0; w.y = a1; w.z = b0; w.w = b1;
        ap[mt][1] = __builtin_bit_cast(bf16x8, w);
      }
    }

    // O += P V ; ell += P 1
#pragma unroll
    for (int ks = 0; ks < 2; ++ks) {
      bf16x8 bv[4];
#pragma unroll
      for (int dt = 0; dt < 4; ++dt) {
        int row  = dt * 16 + l16;
        int slot = (ks * 4 + q4) ^ (row & 7);
        bv[dt] = *(const bf16x8*)&Vs[row * 64 + slot * 8];
      }
#pragma unroll
      for (int mt = 0; mt < 2; ++mt) {
#pragma unroll
        for (int dt = 0; dt < 4; ++dt)
          o[mt][dt] = __builtin_amdgcn_mfma_f32_16x16x32_bf16(ap[mt][ks], bv[dt],
                                                              o[mt][dt], 0, 0, 0);
        o_l[mt] = __builtin_amdgcn_mfma_f32_16x16x32_bf16(ap[mt][ks], ones_f,
                                                          o_l[mt], 0, 0, 0);
      }
    }
  }

  // epilogue: normalize (row-sum broadcast from col-0 lane) and store bf16
#pragma unroll
  for (int mt = 0; mt < 2; ++mt) {
    float inv[4];
#pragma unroll
    for (int r = 0; r < 4; ++r) {
      float lsum = __shfl(o_l[mt][r], lane & 48);   // lane q4*16 holds col 0
      inv[r] = 1.0f / lsum;
    }
#pragma unroll
    for (int dt = 0; dt < 4; ++dt)
#pragma unroll
      for (int r = 0; r < 4; ++r) {
        long row = rowbase + wq0 + mt * 16 + q4 * 4 + r;
        int col = h * 64 + dt * 16 + l16;
        outb[row * 2048 + col] = (bf16)(o[mt][dt][r] * inv[r]);
      }
  }
}

// --------------------------------------------------------------------------------
extern "C" void kernel_launch(void* const* d_in, const int* in_sizes, int n_in,
                              void* d_out, int out_size, void* d_ws, size_t ws_size,
                              hipStream_t stream) {
  const float* x   = (const float*)d_in[0];
  const float* wq  = (const float*)d_in[1];
  const float* wkv = (const float*)d_in[2];
  const float* wo  = (const float*)d_in[3];
  float* out = (float*)d_out;
  char* ws = (char*)d_ws;

  // ws layout (bytes):
  //   xbf  [4096*2048] bf16 @ 0          (16,777,216)  -- reused as attn output
  //   w1   [3072*2048] bf16 @ 16777216   (12,582,912)  -- wq^T | wkv^T ; reused as vT
  //   qkv  [4096*3072] bf16 @ 29360128   (25,165,824)
  //   woT  [2048*2048] bf16 @ 54525952 if ws allows, else aliases qkv after attn
  bf16* xbf  = (bf16*)(ws + 0);
  bf16* w1   = (bf16*)(ws + 16777216);
  bf16* qkv  = (bf16*)(ws + 29360128);
  bf16* attn = xbf;              // xbf dead after gemm1
  bf16* vT   = w1;               // w1 dead after gemm1

  const size_t need_parallel = 54525952u + 8388608u;
  bf16* woT;
  bool woT_early;
  if (ws_size >= need_parallel) {
    woT = (bf16*)(ws + 54525952);
    woT_early = true;
  } else {
    woT = qkv;                   // qkv dead after attention
    woT_early = false;
  }

  // fused prep: z=0 cvt(x), z=1 wq^T, z=2 wkv^T, z=3 wo^T (only if early)
  prep_kernel<<<dim3(64, 64, woT_early ? 4 : 3), 256, 0, stream>>>(
      x, xbf, wq, wkv, wo, w1, woT);

  // qkv = [x@wq | x@wkv]
  gemm_kernel<true><<<dim3(24, 32), 256, 0, stream>>>(xbf, w1, (void*)qkv, 2048, 3072);

  // vT overwrites w1 region (w1 no longer needed)
  transpose_v<<<dim3(16, 128), 256, 0, stream>>>(qkv, vT);

  attn_kernel<<<1024, 256, 0, stream>>>(qkv, vT, attn);

  if (!woT_early)
    transpose_cvt<<<dim3(64, 64), 256, 0, stream>>>(wo, woT, 2048, 2048);

  // out = attn @ wo
  gemm_kernel<false><<<dim3(16, 32), 256, 0, stream>>>(attn, woT, (void*)out, 2048, 2048);
}

// Round 8
// 245.181 us; speedup vs baseline: 1.1453x; 1.0553x over previous
//
#include <hip/hip_runtime.h>

using bf16   = __bf16;
using bf16x8 = __attribute__((ext_vector_type(8))) __bf16;
using f32x4  = __attribute__((ext_vector_type(4))) float;
using u32x4  = __attribute__((ext_vector_type(4))) unsigned;

// B=2 T=2048 D=2048 H=32 KVH=8 HD=64 GROUPS=4 ; M=B*T=4096 ; NQKV=3072
#define T_SEQ 2048
#define NQKV 3072

__device__ __forceinline__ void async_cp16(const bf16* g, bf16* l) {
  __builtin_amdgcn_global_load_lds((__attribute__((address_space(1))) void*)(void*)g,
                                   (__attribute__((address_space(3))) void*)l, 16, 0, 0);
}

// ------------- fused prep: cvt(x) | wq^T | wkv^T | wo^T as z-slices -------------
__global__ __launch_bounds__(256) void prep_kernel(
    const float* __restrict__ x, bf16* __restrict__ xbf,
    const float* __restrict__ wq, const float* __restrict__ wkv,
    const float* __restrict__ wo, bf16* __restrict__ w1,
    bf16* __restrict__ woT) {
  const int z = blockIdx.z;
  if (z == 0) {                 // fp32 -> bf16 convert of x (64x64 blocks = 4096)
    long i = (((long)blockIdx.y * 64 + blockIdx.x) * 256 + threadIdx.x) * 8;
    float4 a = *(const float4*)(x + i);
    float4 c = *(const float4*)(x + i + 4);
    bf16x8 v;
    v[0] = (bf16)a.x; v[1] = (bf16)a.y; v[2] = (bf16)a.z; v[3] = (bf16)a.w;
    v[4] = (bf16)c.x; v[5] = (bf16)c.y; v[6] = (bf16)c.z; v[7] = (bf16)c.w;
    *(bf16x8*)(xbf + i) = v;
    return;
  }
  const float* in; bf16* out; int R, C;
  if (z == 1)      { in = wq;  out = w1;                R = 2048; C = 2048; }
  else if (z == 2) { if (blockIdx.x >= 32) return;
                     in = wkv; out = w1 + 2048L * 2048; R = 2048; C = 1024; }
  else             { in = wo;  out = woT;               R = 2048; C = 2048; }
  __shared__ float tile[32][33];
  const int tc = blockIdx.x * 32;
  const int tr = blockIdx.y * 32;
  const int t = threadIdx.x;
  const int lr = t >> 5;
  const int lc = t & 31;
#pragma unroll
  for (int i = 0; i < 4; ++i)
    tile[lr + i * 8][lc] = in[(size_t)(tr + lr + i * 8) * C + tc + lc];
  __syncthreads();
#pragma unroll
  for (int i = 0; i < 4; ++i)
    out[(size_t)(tc + lr + i * 8) * R + tr + lc] = (bf16)tile[lc][lr + i * 8];
}

// ------------- transpose + convert (standalone, fallback paths) ----------------
__global__ __launch_bounds__(256) void transpose_cvt(const float* __restrict__ in,
                                                     bf16* __restrict__ out,
                                                     int R, int C) {
  __shared__ float tile[32][33];
  const int tc = blockIdx.x * 32;
  const int tr = blockIdx.y * 32;
  const int t = threadIdx.x;
  const int lr = t >> 5;
  const int lc = t & 31;
#pragma unroll
  for (int i = 0; i < 4; ++i)
    tile[lr + i * 8][lc] = in[(size_t)(tr + lr + i * 8) * C + tc + lc];
  __syncthreads();
#pragma unroll
  for (int i = 0; i < 4; ++i)
    out[(size_t)(tc + lr + i * 8) * R + tr + lc] = (bf16)tile[lc][lr + i * 8];
}

// ------------- bf16 transpose of the V block of qkv (fallback path) -------------
__global__ __launch_bounds__(256) void transpose_v(const bf16* __restrict__ in,
                                                   bf16* __restrict__ out) {
  __shared__ bf16 tile[32][33];
  const int c0 = blockIdx.x * 32;   // 0..480
  const int r0 = blockIdx.y * 32;   // 0..4064
  const int t = threadIdx.x;
  const int lr = t >> 5;
  const int lc = t & 31;
#pragma unroll
  for (int i = 0; i < 4; ++i)
    tile[lr + i * 8][lc] = in[(size_t)(r0 + lr + i * 8) * NQKV + 2560 + c0 + lc];
  __syncthreads();
#pragma unroll
  for (int i = 0; i < 4; ++i) {
    int c = c0 + lr + i * 8;
    int r = r0 + lc;
    out[(size_t)((r >> 11) * 512 + c) * 2048 + (r & 2047)] = tile[lc][lr + i * 8];
  }
}

// ------------- GEMM: C[M][N] = A[M][K] * Bt[N][K]^T  (bf16 in, fp32 acc) --------
// r15 changes on the proven r4/m97-structure kernel (55.2us/937TF, MfmaUtil 38%,
// VALU 17% -> ~45% staging-drain stall):
//  * launch_bounds (256,3) -> (256,4): combined regs 60 arch + 64 acc = 124
//    <= 128 cap; LDS 32KB*4 = 128KB <= 160. 4 blocks/CU adds wave-level overlap
//    for the drain. (r3's spill at ,4 was attn-specific: larger live set.)
//    Tripwire: WRITE_SIZE inflation on gemm dispatches = spill -> revert.
//  * V_SPLIT epilogue: V-blocks (n0>=2560) write straight to vT in transposed
//    layout (4 consecutive bf16 per (mt,nt), same scatter class as the normal
//    epilogue), deleting the separate transpose_v kernel + 25MB traffic.
//    vT must NOT alias w1 (gemm reads w1) - placed after woT in ws.
template <bool OUT_BF16, bool V_SPLIT>
__global__ __launch_bounds__(256, 4)
void gemm_kernel(const bf16* __restrict__ A, const bf16* __restrict__ Bt,
                 void* __restrict__ Cout, bf16* __restrict__ vTout,
                 int Kdim, int Ndim) {
  __shared__ __attribute__((aligned(16))) bf16 As[128 * 64];
  __shared__ __attribute__((aligned(16))) bf16 Bs[128 * 64];
  const int tid  = threadIdx.x;
  const int lane = tid & 63;
  const int wave = tid >> 6;
  const int l16  = lane & 15;
  const int q4   = lane >> 4;
  const long m0 = (long)blockIdx.y * 128;
  const long n0 = (long)blockIdx.x * 128;
  const int wm = (wave >> 1) * 64;
  const int wn = (wave & 1) * 64;

  f32x4 acc[4][4] = {};

  for (int k0 = 0; k0 < Kdim; k0 += 64) {
    __syncthreads();
#pragma unroll
    for (int rr = 0; rr < 4; ++rr) {
      int ci  = rr * 256 + tid;     // 16B chunk index 0..1023
      int row = ci >> 3;
      int chp = ci & 7;             // swizzled LDS chunk slot
      int ch  = chp ^ (row & 7);    // global chunk
      async_cp16(A + (m0 + row) * (long)Kdim + k0 + ch * 8, &As[ci * 8]);
      async_cp16(Bt + (n0 + row) * (long)Kdim + k0 + ch * 8, &Bs[ci * 8]);
    }
    __syncthreads();
#pragma unroll
    for (int ks = 0; ks < 2; ++ks) {
      bf16x8 af[4], bfr[4];
#pragma unroll
      for (int mt = 0; mt < 4; ++mt) {
        int row = wm + mt * 16 + l16;
        int chp = (ks * 4 + q4) ^ (row & 7);
        af[mt] = *(const bf16x8*)&As[row * 64 + chp * 8];
      }
#pragma unroll
      for (int nt = 0; nt < 4; ++nt) {
        int row = wn + nt * 16 + l16;
        int chp = (ks * 4 + q4) ^ (row & 7);
        bfr[nt] = *(const bf16x8*)&Bs[row * 64 + chp * 8];
      }
#pragma unroll
      for (int mt = 0; mt < 4; ++mt)
#pragma unroll
        for (int nt = 0; nt < 4; ++nt)
          acc[mt][nt] = __builtin_amdgcn_mfma_f32_16x16x32_bf16(af[mt], bfr[nt],
                                                                acc[mt][nt], 0, 0, 0);
    }
  }

  if constexpr (V_SPLIT) {
    if (n0 >= 2560) {   // V block: write transposed directly to vT
#pragma unroll
      for (int mt = 0; mt < 4; ++mt)
#pragma unroll
        for (int nt = 0; nt < 4; ++nt)
#pragma unroll
          for (int r = 0; r < 4; ++r) {
            long row = m0 + wm + mt * 16 + q4 * 4 + r;
            long c   = n0 + wn + nt * 16 + l16 - 2560;
            vTout[((row >> 11) * 512 + c) * 2048 + (row & 2047)] =
                (bf16)acc[mt][nt][r];
          }
      return;
    }
  }
#pragma unroll
  for (int mt = 0; mt < 4; ++mt)
#pragma unroll
    for (int nt = 0; nt < 4; ++nt)
#pragma unroll
      for (int r = 0; r < 4; ++r) {
        long row = m0 + wm + mt * 16 + q4 * 4 + r;
        long col = n0 + wn + nt * 16 + l16;
        float v = acc[mt][nt][r];
        if constexpr (OUT_BF16)
          ((bf16*)Cout)[row * Ndim + col] = (bf16)v;
        else
          ((float*)Cout)[row * Ndim + col] = v;
      }
}

// ------------- causal GQA flash attention ---------------------------------------
// (unchanged from r14: T14 async-STAGE, operand-swapped QK^T, in-register P
// transpose via cvt_pk + permlane32/16 swaps, bare v_exp_f32, (256,3).)
__global__ __launch_bounds__(256, 3)
void attn_kernel(const bf16* __restrict__ qkv, const bf16* __restrict__ vT,
                 bf16* __restrict__ outb) {
  __shared__ __attribute__((aligned(16))) bf16 Ks[64 * 64];   // swizzled chunks
  __shared__ __attribute__((aligned(16))) bf16 Vs[64 * 64];   // V^T tile, swizzled

  const int tid  = threadIdx.x;
  const int lane = tid & 63;
  const int wave = tid >> 6;
  const int l16  = lane & 15;
  const int q4   = lane >> 4;

  const int bid = blockIdx.x;
  const int qt  = 15 - (bid >> 6);   // heavy q-tiles dispatched first
  const int bh  = bid & 63;
  const int b   = bh >> 5;
  const int h   = bh & 31;
  const int kvh = h >> 2;
  const long rowbase = (long)b * T_SEQ;

  const int qrow0 = qt * 128;
  const int wq0   = qrow0 + wave * 32;
  const float cexp = 0.125f * 1.4426950408889634f;  // scale * log2(e), folded into Q

  // Q fragments in registers, pre-scaled by cexp (so P = exp2(S) directly)
  bf16x8 aq[2][2];
#pragma unroll
  for (int mt = 0; mt < 2; ++mt)
#pragma unroll
    for (int ks = 0; ks < 2; ++ks) {
      bf16x8 v = *(const bf16x8*)(qkv +
          (rowbase + wq0 + mt * 16 + l16) * (long)NQKV + h * 64 + ks * 32 + q4 * 8);
#pragma unroll
      for (int i = 0; i < 8; ++i) v[i] = (bf16)((float)v[i] * cexp);
      aq[mt][ks] = v;
    }

  // ones B-fragment: B[k][n=0]=1 -> accumulates row-sums of P into col 0
  bf16x8 ones_f;
#pragma unroll
  for (int i = 0; i < 8; ++i) ones_f[i] = (l16 == 0) ? (bf16)1.0f : (bf16)0.0f;

  f32x4 o[2][4] = {};
  f32x4 o_l[2] = {};

  const bf16* kbase = qkv + rowbase * (long)NQKV + 2048 + kvh * 64;
  const bf16* vbase = vT + ((long)b * 512 + kvh * 64) * 2048;

  const int ntiles = (qrow0 + 128) >> 6;

  // T14 prologue: tile 0 -> regs
  bf16x8 kr[2], vr[2];
#pragma unroll
  for (int h2 = 0; h2 < 2; ++h2) {
    int ci = h2 * 256 + tid, row = ci >> 3, ch = (ci & 7) ^ (row & 7);
    kr[h2] = *(const bf16x8*)(kbase + (long)row * NQKV + ch * 8);
    vr[h2] = *(const bf16x8*)(vbase + (long)row * 2048 + ch * 8);
  }

  for (int t = 0; t < ntiles; ++t) {
    const int j0 = t * 64;
    __syncthreads();                     // all waves done reading prev tile's LDS
#pragma unroll
    for (int h2 = 0; h2 < 2; ++h2) {     // regs -> LDS
      int ci = h2 * 256 + tid;
      *(bf16x8*)&Ks[ci * 8] = kr[h2];
      *(bf16x8*)&Vs[ci * 8] = vr[h2];
    }
    __syncthreads();                     // LDS ready
    if (t + 1 < ntiles) {                // issue next tile's loads; land during compute
      const int jn = j0 + 64;
#pragma unroll
      for (int h2 = 0; h2 < 2; ++h2) {
        int ci = h2 * 256 + tid, row = ci >> 3, ch = (ci & 7) ^ (row & 7);
        kr[h2] = *(const bf16x8*)(kbase + (long)(jn + row) * NQKV + ch * 8);
        vr[h2] = *(const bf16x8*)(vbase + (long)row * 2048 + jn + ch * 8);
      }
    }
    if (j0 > wq0 + 31) continue;   // tile entirely above diagonal for this wave

    // S^T = K Q^T  (operand-swapped: tiles [kv = nt][q = mt])
    f32x4 s[2][4] = {};
#pragma unroll
    for (int ks = 0; ks < 2; ++ks) {
      bf16x8 bk[4];
#pragma unroll
      for (int nt = 0; nt < 4; ++nt) {
        int row  = nt * 16 + l16;
        int slot = (ks * 4 + q4) ^ (row & 7);
        bk[nt] = *(const bf16x8*)&Ks[row * 64 + slot * 8];
      }
#pragma unroll
      for (int mt = 0; mt < 2; ++mt)
#pragma unroll
        for (int nt = 0; nt < 4; ++nt)
          s[mt][nt] = __builtin_amdgcn_mfma_f32_16x16x32_bf16(bk[nt], aq[mt][ks],
                                                              s[mt][nt], 0, 0, 0);
    }

    if (j0 + 63 > wq0) {   // diagonal tile: causal mask (S^T: row=kv, col=q)
#pragma unroll
      for (int mt = 0; mt < 2; ++mt)
#pragma unroll
        for (int nt = 0; nt < 4; ++nt)
#pragma unroll
          for (int r = 0; r < 4; ++r) {
            int rg = wq0 + mt * 16 + l16;          // q row
            int cg = j0 + nt * 16 + q4 * 4 + r;    // kv col
            if (cg > rg) s[mt][nt][r] = -__builtin_inff();
          }
    }

    // P = exp2(S^T) via bare v_exp_f32; pack pairs with v_cvt_pk_bf16_f32;
    // route packed words into PV A-fragments with permlane32/16_swap.
    bf16x8 ap[2][2];
#pragma unroll
    for (int mt = 0; mt < 2; ++mt) {
      unsigned pk0, pk1, pk2, pk3, pk4, pk5, pk6, pk7;  // pk[nt][j], named scalars
      {
        float p0 = __builtin_amdgcn_exp2f(s[mt][0][0]);
        float p1 = __builtin_amdgcn_exp2f(s[mt][0][1]);
        float p2 = __builtin_amdgcn_exp2f(s[mt][0][2]);
        float p3 = __builtin_amdgcn_exp2f(s[mt][0][3]);
        asm("v_cvt_pk_bf16_f32 %0, %1, %2" : "=v"(pk0) : "v"(p0), "v"(p1));
        asm("v_cvt_pk_bf16_f32 %0, %1, %2" : "=v"(pk1) : "v"(p2), "v"(p3));
      }
      {
        float p0 = __builtin_amdgcn_exp2f(s[mt][1][0]);
        float p1 = __builtin_amdgcn_exp2f(s[mt][1][1]);
        float p2 = __builtin_amdgcn_exp2f(s[mt][1][2]);
        float p3 = __builtin_amdgcn_exp2f(s[mt][1][3]);
        asm("v_cvt_pk_bf16_f32 %0, %1, %2" : "=v"(pk2) : "v"(p0), "v"(p1));
        asm("v_cvt_pk_bf16_f32 %0, %1, %2" : "=v"(pk3) : "v"(p2), "v"(p3));
      }
      {
        float p0 = __builtin_amdgcn_exp2f(s[mt][2][0]);
        float p1 = __builtin_amdgcn_exp2f(s[mt][2][1]);
        float p2 = __builtin_amdgcn_exp2f(s[mt][2][2]);
        float p3 = __builtin_amdgcn_exp2f(s[mt][2][3]);
        asm("v_cvt_pk_bf16_f32 %0, %1, %2" : "=v"(pk4) : "v"(p0), "v"(p1));
        asm("v_cvt_pk_bf16_f32 %0, %1, %2" : "=v"(pk5) : "v"(p2), "v"(p3));
      }
      {
        float p0 = __builtin_amdgcn_exp2f(s[mt][3][0]);
        float p1 = __builtin_amdgcn_exp2f(s[mt][3][1]);
        float p2 = __builtin_amdgcn_exp2f(s[mt][3][2]);
        float p3 = __builtin_amdgcn_exp2f(s[mt][3][3]);
        asm("v_cvt_pk_bf16_f32 %0, %1, %2" : "=v"(pk6) : "v"(p0), "v"(p1));
        asm("v_cvt_pk_bf16_f32 %0, %1, %2" : "=v"(pk7) : "v"(p2), "v"(p3));
      }
      // ks = 0: sources pk[0][*], pk[1][*]
      {
        unsigned a0 = pk0, b0 = pk2;
        asm("v_permlane32_swap_b32 %0, %1" : "+v"(a0), "+v"(b0));
        asm("v_permlane16_swap_b32 %0, %1" : "+v"(a0), "+v"(b0));
        unsigned a1 = pk1, b1 = pk3;
        asm("v_permlane32_swap_b32 %0, %1" : "+v"(a1), "+v"(b1));
        asm("v_permlane16_swap_b32 %0, %1" : "+v"(a1), "+v"(b1));
        u32x4 w; w.x = a0; w.y = a1; w.z = b0; w.w = b1;
        ap[mt][0] = __builtin_bit_cast(bf16x8, w);
      }
      // ks = 1: sources pk[2][*], pk[3][*]
      {
        unsigned a0 = pk4, b0 = pk6;
        asm("v_permlane32_swap_b32 %0, %1" : "+v"(a0), "+v"(b0));
        asm("v_permlane16_swap_b32 %0, %1" : "+v"(a0), "+v"(b0));
        unsigned a1 = pk5, b1 = pk7;
        asm("v_permlane32_swap_b32 %0, %1" : "+v"(a1), "+v"(b1));
        asm("v_permlane16_swap_b32 %0, %1" : "+v"(a1), "+v"(b1));
        u32x4 w; w.x = a0; w.y = a1; w.z = b0; w.w = b1;
        ap[mt][1] = __builtin_bit_cast(bf16x8, w);
      }
    }

    // O += P V ; ell += P 1
#pragma unroll
    for (int ks = 0; ks < 2; ++ks) {
      bf16x8 bv[4];
#pragma unroll
      for (int dt = 0; dt < 4; ++dt) {
        int row  = dt * 16 + l16;
        int slot = (ks * 4 + q4) ^ (row & 7);
        bv[dt] = *(const bf16x8*)&Vs[row * 64 + slot * 8];
      }
#pragma unroll
      for (int mt = 0; mt < 2; ++mt) {
#pragma unroll
        for (int dt = 0; dt < 4; ++dt)
          o[mt][dt] = __builtin_amdgcn_mfma_f32_16x16x32_bf16(ap[mt][ks], bv[dt],
                                                              o[mt][dt], 0, 0, 0);
        o_l[mt] = __builtin_amdgcn_mfma_f32_16x16x32_bf16(ap[mt][ks], ones_f,
                                                          o_l[mt], 0, 0, 0);
      }
    }
  }

  // epilogue: normalize (row-sum broadcast from col-0 lane) and store bf16
#pragma unroll
  for (int mt = 0; mt < 2; ++mt) {
    float inv[4];
#pragma unroll
    for (int r = 0; r < 4; ++r) {
      float lsum = __shfl(o_l[mt][r], lane & 48);   // lane q4*16 holds col 0
      inv[r] = 1.0f / lsum;
    }
#pragma unroll
    for (int dt = 0; dt < 4; ++dt)
#pragma unroll
      for (int r = 0; r < 4; ++r) {
        long row = rowbase + wq0 + mt * 16 + q4 * 4 + r;
        int col = h * 64 + dt * 16 + l16;
        outb[row * 2048 + col] = (bf16)(o[mt][dt][r] * inv[r]);
      }
  }
}

// --------------------------------------------------------------------------------
extern "C" void kernel_launch(void* const* d_in, const int* in_sizes, int n_in,
                              void* d_out, int out_size, void* d_ws, size_t ws_size,
                              hipStream_t stream) {
  const float* x   = (const float*)d_in[0];
  const float* wq  = (const float*)d_in[1];
  const float* wkv = (const float*)d_in[2];
  const float* wo  = (const float*)d_in[3];
  float* out = (float*)d_out;
  char* ws = (char*)d_ws;

  // ws layout (bytes):
  //   xbf  [4096*2048] bf16 @ 0          (16,777,216)  -- reused as attn output
  //   w1   [3072*2048] bf16 @ 16777216   (12,582,912)  -- wq^T | wkv^T
  //   qkv  [4096*3072] bf16 @ 29360128   (25,165,824)  -- ends 54,525,952
  //   woT  [2048*2048] bf16 @ 54525952   ( 8,388,608)  -- ends 62,914,560
  //   vT   [2*512*2048] bf16 @ 62914560  ( 4,194,304)  -- ends 67,108,864
  bf16* xbf  = (bf16*)(ws + 0);
  bf16* w1   = (bf16*)(ws + 16777216);
  bf16* qkv  = (bf16*)(ws + 29360128);
  bf16* attn = xbf;              // xbf dead after gemm1

  const bool fused_v  = ws_size >= 67108864u;   // vT slot after woT
  const bool woT_early = ws_size >= 62914560u;

  bf16* woT = woT_early ? (bf16*)(ws + 54525952) : qkv;   // qkv dead after attn
  bf16* vT  = fused_v   ? (bf16*)(ws + 62914560) : w1;    // w1 dead after gemm1

  // fused prep: z=0 cvt(x), z=1 wq^T, z=2 wkv^T, z=3 wo^T (only if early)
  prep_kernel<<<dim3(64, 64, woT_early ? 4 : 3), 256, 0, stream>>>(
      x, xbf, wq, wkv, wo, w1, woT);

  // qkv = [x@wq | x@wkv]; fused path also writes V directly to vT (transposed)
  if (fused_v) {
    gemm_kernel<true, true><<<dim3(24, 32), 256, 0, stream>>>(
        xbf, w1, (void*)qkv, vT, 2048, 3072);
  } else {
    gemm_kernel<true, false><<<dim3(24, 32), 256, 0, stream>>>(
        xbf, w1, (void*)qkv, nullptr, 2048, 3072);
    transpose_v<<<dim3(16, 128), 256, 0, stream>>>(qkv, vT);  // vT = w1 (dead)
  }

  attn_kernel<<<1024, 256, 0, stream>>>(qkv, vT, attn);

  if (!woT_early)
    transpose_cvt<<<dim3(64, 64), 256, 0, stream>>>(wo, woT, 2048, 2048);

  // out = attn @ wo
  gemm_kernel<false, false><<<dim3(16, 32), 256, 0, stream>>>(
      attn, woT, (void*)out, nullptr, 2048, 2048);
}